// Round 1
// baseline (342.890 us; speedup 1.0000x reference)
//
#include <hip/hip_runtime.h>

// QuantumRecurrentUnit, exact Heisenberg closed form.
//   rev_q = (p_q + x_q)/2pi ;  sa=sin, ca=cos of the angle
//   p_q' = cos(th_q)*prefixprod_{j<=q} ca_j - sin(th_q)*(q<5 ? sa_q*sa_{q+1} : sa_5)
//
// v2: ZERO-LDS register-resident design. Each lane owns its 8 output rows
// (48 VGPRs, loaded once). Burn-in rows at step i (superstep k=i>>3) are the
// chunk of wave-local lane l+k-4 -> fetched with 6 ds_bpermute (uniform shift)
// instead of LDS reads; output steps (k==4) read own registers directly.
// Halo (lanes 0..3 of a wave, k<4): wave 0 = pre-t=0 junk (exact reset fixes,
// as before); wave 1 = masked 4-lane global re-read of L1-hot lines.
// Removing the 25 KB LDS stage lifts the 6-blocks/CU residency cap: all
// 8 blocks/CU resident (no tranche tail), 16 waves/CU at <=128 VGPR.
// Angle fetch is double-buffered one step ahead so bpermute/load latency
// hides under the previous step's sin/cos chain.

constexpr int T = 1024;
constexpr int NQ = 6;
constexpr int S = 8;         // output steps per lane
constexpr int W = 32;        // burn-in steps
constexpr int TOT = W + S;   // 40
constexpr float INV2PI = 0.15915494309189535f;  // v_sin/v_cos take revolutions

__global__ __launch_bounds__(128, 4) void qru_kernel(const float* __restrict__ x,
                                                     const float* __restrict__ w,
                                                     float* __restrict__ out) {
  const int L = threadIdx.x;   // window index within chain, 0..127
  const int l = L & 63;        // wave-local lane
  const int chain = blockIdx.x;
  const float* __restrict__ xb = x + (size_t)chain * (T * 16);
  float* __restrict__ ob = out + (size_t)chain * (T * NQ);

  // ---- own chunk: rows [8L, 8L+8), 6 angles each, pre-scaled by 1/2pi ----
  float f[8][NQ];
#pragma unroll
  for (int m = 0; m < 8; ++m) {
    const float* rp = xb + (size_t)(8 * L + m) * 16;
    const float4 v4 = *(const float4*)rp;
    const float2 v2 = *(const float2*)(rp + 4);
    f[m][0] = v4.x * INV2PI;
    f[m][1] = v4.y * INV2PI;
    f[m][2] = v4.z * INV2PI;
    f[m][3] = v4.w * INV2PI;
    f[m][4] = v2.x * INV2PI;
    f[m][5] = v2.y * INV2PI;
  }

  float cth[NQ], sth[NQ];
#pragma unroll
  for (int q = 0; q < NQ; ++q) {
    const float th = w[q];
    cth[q] = cosf(th);
    sth[q] = sinf(th);
  }

  float p[NQ];
#pragma unroll
  for (int q = 0; q < NQ; ++q) p[q] = 0.0f;

  const int tbase = L * S - W;  // lanes 0..3 (wave 0): window crosses t=0

  float aA[NQ], aB[NQ];  // double-buffered per-step angles

  // Fetch the 6 angles for step I into DST.
  // Row of step I is 8L + I - 32 = chunk row (I&7) of owner lane l + (I>>3) - 4.
#define FETCH(I, DST)                                                          \
  do {                                                                         \
    const int k_ = (I) >> 3;                                                   \
    const int m_ = (I) & 7;                                                    \
    if (k_ == 4) { /* output steps: own registers, no ds traffic */            \
      _Pragma("unroll") for (int q_ = 0; q_ < NQ; ++q_) DST[q_] = f[m_][q_];   \
    } else {                                                                   \
      const int src_ = l + k_ - 4;                                             \
      _Pragma("unroll") for (int q_ = 0; q_ < NQ; ++q_)                        \
          DST[q_] = __shfl(f[m_][q_], src_, 64);                               \
      if (src_ < 0) { /* lanes 0..3: out-of-wave halo */                       \
        int r_ = tbase + (I);                                                  \
        r_ = r_ < 0 ? 0 : r_;  /* wave 0 pre-t=0: junk row, reset follows */   \
        const float* rp_ = xb + (size_t)r_ * 16;                               \
        const float4 v4_ = *(const float4*)rp_;                                \
        const float2 v2_ = *(const float2*)(rp_ + 4);                          \
        DST[0] = v4_.x * INV2PI;                                               \
        DST[1] = v4_.y * INV2PI;                                               \
        DST[2] = v4_.z * INV2PI;                                               \
        DST[3] = v4_.w * INV2PI;                                               \
        DST[4] = v2_.x * INV2PI;                                               \
        DST[5] = v2_.y * INV2PI;                                               \
      }                                                                        \
    }                                                                          \
  } while (0)

  // One recurrence step using CUR; prefetch step I+1 into NXT first.
#define STEP(I, CUR, NXT)                                                      \
  do {                                                                         \
    if ((I) + 1 < TOT) FETCH((I) + 1, NXT);                                    \
    if ((I) >= 8 && (I) <= 32 && ((I) & 7) == 0) {                             \
      const bool rs_ = (tbase + (I) == 0);                                     \
      _Pragma("unroll") for (int q_ = 0; q_ < NQ; ++q_)                        \
          p[q_] = rs_ ? 0.0f : p[q_];                                          \
    }                                                                          \
    float sa_[NQ], ca_[NQ];                                                    \
    _Pragma("unroll") for (int q_ = 0; q_ < NQ; ++q_) {                        \
      const float rev_ = fmaf(p[q_], INV2PI, CUR[q_]);                         \
      sa_[q_] = __builtin_amdgcn_sinf(rev_);                                   \
      ca_[q_] = __builtin_amdgcn_cosf(rev_);                                   \
    }                                                                          \
    const float t01_ = ca_[0] * ca_[1];                                        \
    const float t23_ = ca_[2] * ca_[3];                                        \
    const float t45_ = ca_[4] * ca_[5];                                        \
    const float P2_ = t01_ * ca_[2];                                           \
    const float P3_ = t01_ * t23_;                                             \
    const float P4_ = P3_ * ca_[4];                                            \
    const float P5_ = P3_ * t45_;                                              \
    p[0] = cth[0] * ca_[0] - sth[0] * (sa_[0] * sa_[1]);                       \
    p[1] = cth[1] * t01_ - sth[1] * (sa_[1] * sa_[2]);                         \
    p[2] = cth[2] * P2_ - sth[2] * (sa_[2] * sa_[3]);                          \
    p[3] = cth[3] * P3_ - sth[3] * (sa_[3] * sa_[4]);                          \
    p[4] = cth[4] * P4_ - sth[4] * (sa_[4] * sa_[5]);                          \
    p[5] = cth[5] * P5_ - sth[5] * sa_[5];                                     \
    if ((I) >= W) {                                                            \
      float2* op_ = (float2*)(ob + (size_t)(tbase + (I)) * NQ);                \
      op_[0] = make_float2(p[0], p[1]);                                        \
      op_[1] = make_float2(p[2], p[3]);                                        \
      op_[2] = make_float2(p[4], p[5]);                                        \
    }                                                                          \
  } while (0)

  FETCH(0, aA);
#pragma unroll
  for (int i = 0; i < TOT; i += 2) {
    STEP(i, aA, aB);
    STEP(i + 1, aB, aA);
  }
#undef FETCH
#undef STEP
}

extern "C" void kernel_launch(void* const* d_in, const int* in_sizes, int n_in,
                              void* d_out, int out_size, void* d_ws, size_t ws_size,
                              hipStream_t stream) {
  const float* x = (const float*)d_in[0];
  const float* w = (const float*)d_in[1];
  float* out = (float*)d_out;
  const int B = in_sizes[0] / (T * 16);  // 2048 chains
  qru_kernel<<<B, 128, 0, stream>>>(x, w, out);
}

// Round 2
// 270.369 us; speedup vs baseline: 1.2682x; 1.2682x over previous
//
#include <hip/hip_runtime.h>

// QuantumRecurrentUnit, exact Heisenberg closed form.
//   rev_q = (p_q + x_q)/2pi ;  sa=sin, ca=cos of the angle
//   p_q' = cos(th_q)*prefixprod_{j<=q} ca_j - sin(th_q)*(q<5 ? sa_q*sa_{q+1} : sa_5)
//
// v3: zero-LDS, zero-shuffle, ALL-GLOBAL deep-prefetch design.
// Per-step angle addresses depend only on (threadIdx, step) -- never on the
// recurrence -- so each lane streams its own 40 rows straight from global,
// software-pipelined PF=4 steps deep (8 loads in flight, issued ~4 dependent
// chains ahead of use). Row re-reads (<=5 lanes per row, same block) hit
// L1/L2/L3; x (128 MB) fits in the 256 MB Infinity Cache, so HBM fetch stays
// at the compulsory ~64 MB.
// No LDS => no 6-blocks/CU residency cap, no tranche tail, no syncthreads:
// all 16 waves/CU co-resident in one generation. ~80 VGPRs (4x6 pipeline
// buffers instead of v2's 48-reg chunk array, which the compiler demoted to
// scratch under launch_bounds -- 253 MB phantom WRITE_SIZE). No min-waves
// clause: occupancy is grid-limited anyway; don't invite spills.

constexpr int T = 1024;
constexpr int NQ = 6;
constexpr int S = 8;         // output steps per lane
constexpr int W = 32;        // burn-in steps
constexpr int TOT = W + S;   // 40
constexpr int PF = 4;        // prefetch depth (TOT % PF == 0)
constexpr float INV2PI = 0.15915494309189535f;  // v_sin/v_cos take revolutions

__global__ __launch_bounds__(128) void qru_kernel(const float* __restrict__ x,
                                                  const float* __restrict__ w,
                                                  float* __restrict__ out) {
  const int L = threadIdx.x;   // window index within chain, 0..127
  const int chain = blockIdx.x;
  const float* __restrict__ xb = x + (size_t)chain * (T * 16);
  float* __restrict__ ob = out + (size_t)chain * (T * NQ);
  const int tbase = L * S - W;  // lanes 0..3: window crosses t=0

  float cth[NQ], sth[NQ];
#pragma unroll
  for (int q = 0; q < NQ; ++q) {
    const float th = w[q];
    cth[q] = cosf(th);
    sth[q] = sinf(th);
  }

  float p[NQ];
#pragma unroll
  for (int q = 0; q < NQ; ++q) p[q] = 0.0f;

  // Pipeline buffers: raw (unscaled) angles for steps I, I+1, I+2, I+3.
  float b0[NQ], b1[NQ], b2[NQ], b3[NQ];

  // Load the 6 raw angles of step I's row into B (float4+float2, 16B-aligned).
#define LOADROW(I, B)                                                          \
  do {                                                                         \
    int r_ = tbase + (I);                                                      \
    r_ = r_ < 0 ? 0 : r_; /* burn-in underrun: dummy row 0, exact reset follows */ \
    const float* rp_ = xb + (size_t)r_ * 16;                                   \
    const float4 v4_ = *(const float4*)rp_;                                    \
    const float2 v2_ = *(const float2*)(rp_ + 4);                              \
    B[0] = v4_.x;                                                              \
    B[1] = v4_.y;                                                              \
    B[2] = v4_.z;                                                              \
    B[3] = v4_.w;                                                              \
    B[4] = v2_.x;                                                              \
    B[5] = v2_.y;                                                              \
  } while (0)

  // One recurrence step consuming B; refills B with step I+PF right after the
  // buffer is freed (rev computed), so the load leads its use by 4 full steps.
#define STEP(I, B)                                                             \
  do {                                                                         \
    if ((I) >= 8 && (I) <= 32 && ((I)&7) == 0) {                               \
      const bool rs_ = (tbase + (I) == 0);                                     \
      _Pragma("unroll") for (int q_ = 0; q_ < NQ; ++q_)                        \
          p[q_] = rs_ ? 0.0f : p[q_];                                          \
    }                                                                          \
    float rev_[NQ];                                                            \
    _Pragma("unroll") for (int q_ = 0; q_ < NQ; ++q_)                          \
        rev_[q_] = (p[q_] + B[q_]) * INV2PI;                                   \
    if ((I) + PF < TOT) LOADROW((I) + PF, B); /* buffer free: issue refill */  \
    float sa_[NQ], ca_[NQ];                                                    \
    _Pragma("unroll") for (int q_ = 0; q_ < NQ; ++q_) {                        \
      sa_[q_] = __builtin_amdgcn_sinf(rev_[q_]);                               \
      ca_[q_] = __builtin_amdgcn_cosf(rev_[q_]);                               \
    }                                                                          \
    const float t01_ = ca_[0] * ca_[1];                                        \
    const float t23_ = ca_[2] * ca_[3];                                        \
    const float t45_ = ca_[4] * ca_[5];                                        \
    const float P2_ = t01_ * ca_[2];                                           \
    const float P3_ = t01_ * t23_;                                             \
    const float P4_ = P3_ * ca_[4];                                            \
    const float P5_ = P3_ * t45_;                                              \
    p[0] = cth[0] * ca_[0] - sth[0] * (sa_[0] * sa_[1]);                       \
    p[1] = cth[1] * t01_ - sth[1] * (sa_[1] * sa_[2]);                         \
    p[2] = cth[2] * P2_ - sth[2] * (sa_[2] * sa_[3]);                          \
    p[3] = cth[3] * P3_ - sth[3] * (sa_[3] * sa_[4]);                          \
    p[4] = cth[4] * P4_ - sth[4] * (sa_[4] * sa_[5]);                          \
    p[5] = cth[5] * P5_ - sth[5] * sa_[5];                                     \
    if ((I) >= W) { /* uniform branch: I is compile-time */                    \
      float2* op_ = (float2*)(ob + (size_t)(tbase + (I)) * NQ);                \
      op_[0] = make_float2(p[0], p[1]);                                        \
      op_[1] = make_float2(p[2], p[3]);                                        \
      op_[2] = make_float2(p[4], p[5]);                                        \
    }                                                                          \
  } while (0)

  LOADROW(0, b0);
  LOADROW(1, b1);
  LOADROW(2, b2);
  LOADROW(3, b3);

#pragma unroll
  for (int i = 0; i < TOT; i += PF) {  // 10 iterations, fully unrolled
    STEP(i + 0, b0);
    STEP(i + 1, b1);
    STEP(i + 2, b2);
    STEP(i + 3, b3);
  }
#undef LOADROW
#undef STEP
}

extern "C" void kernel_launch(void* const* d_in, const int* in_sizes, int n_in,
                              void* d_out, int out_size, void* d_ws, size_t ws_size,
                              hipStream_t stream) {
  const float* x = (const float*)d_in[0];
  const float* w = (const float*)d_in[1];
  float* out = (float*)d_out;
  const int B = in_sizes[0] / (T * 16);  // 2048 chains
  qru_kernel<<<B, 128, 0, stream>>>(x, w, out);
}